// Round 8
// baseline (433.365 us; speedup 1.0000x reference)
//
#include <hip/hip_runtime.h>

// ProvidenceLSTM fused, round 8: 2 batch elements per wave, no cross-lane ops
// in the recurrence. Lanes 0..31 = batch bA, lanes 32..63 = bB (lens sorted
// descending => lenA >= lenB, so lenA is the wave-uniform loop bound).
// Lane j<20 owns unit j with ALL 4 gate rows as two packed-f2 dots (i,g)/(f,o)
// -> c,h lane-local, zero shuffles. Weights (batch-independent) pinned once in
// VGPRs (~176). h broadcast per half via one LDS row (write + 5 broadcast
// ds_read_b128, latency hidden under the 48-FMA x-dot; same-wave DS is
// in-order). x staged through LDS in 30-step double-buffered chunks. Heads
// (alpha/beta) computed at chunk granularity from an LDS h-stage; t>=len tail
// is constant. Single kernel, no workspace.

typedef float f2 __attribute__((ext_vector_type(2)));

constexpr int T_ = 512;
constexpr int B_ = 2048;
constexpr int I_ = 24;
constexpr int H_ = 20;
constexpr int CH = 30;                    // steps per x-chunk
constexpr int XBUF = 2 * CH * I_;         // 1440 floats per x buffer
constexpr size_t TB_ = (size_t)T_ * B_;

__device__ __forceinline__ float sigm(float x) {
  return __fdividef(1.0f, 1.0f + __expf(-x));
}
__device__ __forceinline__ float tanh_fast(float x) {
  return 1.0f - __fdividef(2.0f, 1.0f + __expf(2.0f * x));
}
__device__ __forceinline__ float softplus_fast(float x) {
  return __logf(1.0f + __expf(x));
}
__device__ __forceinline__ f2 pkfma(f2 a, float s, f2 c) {
  return __builtin_elementwise_fma(a, (f2){s, s}, c);
}

__global__ __launch_bounds__(64, 1)
void lstm_fused(const float* __restrict__ x,      // [T,B,I]
                const int* __restrict__ lens,     // [B]
                const float* __restrict__ W_ih,   // [80,24]
                const float* __restrict__ W_hh,   // [80,20]
                const float* __restrict__ b_ih,   // [80]
                const float* __restrict__ b_hh,   // [80]
                const float* __restrict__ W_a, const float* __restrict__ b_a,
                const float* __restrict__ W_b, const float* __restrict__ b_b,
                float* __restrict__ out)          // alpha[T*B] ++ beta[T*B]
{
  const int lane = threadIdx.x;             // 0..63
  const int hf   = lane >> 5;               // half: 0 -> bA, 1 -> bB
  const int j    = lane & 31;               // unit within half (active j<20)
  const int bA   = blockIdx.x * 2;
  const int b    = bA + hf;
  const int lenA = lens[bA];                // wave-uniform loop bound
  const int len  = lens[b];                 // per-half output bound

  __shared__ float xs[2 * XBUF];            // x double buffer (11.5 KB)
  __shared__ float hst[2][CH][24];          // h stage for chunk heads (5.8 KB)
  __shared__ float hbuf[2][24];             // per-half h broadcast row

  const int jj = (j < H_) ? j : 0;          // idle lanes duplicate row 0
  // Gate rows (PyTorch order i,f,g,o): i=jj, f=H+jj, g=2H+jj, o=3H+jj.
  f2 Wxig[I_], Wxfo[I_];
  #pragma unroll
  for (int k = 0; k < I_; ++k) {
    Wxig[k] = (f2){ W_ih[jj * I_ + k],          W_ih[(2 * H_ + jj) * I_ + k] };
    Wxfo[k] = (f2){ W_ih[(H_ + jj) * I_ + k],   W_ih[(3 * H_ + jj) * I_ + k] };
  }
  f2 Whig[H_], Whfo[H_];
  #pragma unroll
  for (int k = 0; k < H_; ++k) {
    Whig[k] = (f2){ W_hh[jj * H_ + k],          W_hh[(2 * H_ + jj) * H_ + k] };
    Whfo[k] = (f2){ W_hh[(H_ + jj) * H_ + k],   W_hh[(3 * H_ + jj) * H_ + k] };
  }
  const f2 big = { b_ih[jj] + b_hh[jj],
                   b_ih[2 * H_ + jj] + b_hh[2 * H_ + jj] };
  const f2 bfo = { b_ih[H_ + jj] + b_hh[H_ + jj],
                   b_ih[3 * H_ + jj] + b_hh[3 * H_ + jj] };

  f2 wab[H_];                               // uniform -> SGPRs
  #pragma unroll
  for (int k = 0; k < H_; ++k) wab[k] = (f2){ W_a[k], W_b[k] };
  const float ba = b_a[0], bb = b_b[0];

  // --- per-lane x staging geometry: 6 float4 per lane covers 2*2880B chunk ---
  int sA_[6], fA_[6], bat_[6];
  #pragma unroll
  for (int r = 0; r < 6; ++r) {
    const int fi  = r * 256 + lane * 4;     // float index in chunk (valid <1440)
    const int bt  = fi / 720;
    const int rem = fi - bt * 720;
    bat_[r] = bt; sA_[r] = rem / 24; fA_[r] = rem - (rem / 24) * 24;
  }

  float4 p[6];
  auto GLOAD = [&](int ch) {
    #pragma unroll
    for (int r = 0; r < 6; ++r) {
      if (r < 5 || lane < 40) {
        int t = ch * CH + sA_[r]; t = t < T_ ? t : T_ - 1;
        p[r] = *(const float4*)(x + ((size_t)t * B_ + (bA + bat_[r])) * I_ + fA_[r]);
      }
    }
  };
  auto DSWRITE = [&](int buf) {
    #pragma unroll
    for (int r = 0; r < 6; ++r)
      if (r < 5 || lane < 40)
        *(float4*)(&xs[buf * XBUF + r * 256 + lane * 4]) = p[r];
  };

  float xn[I_];
  auto READX = [&](int buf, int s) {
    const float4* q = (const float4*)(&xs[buf * XBUF + hf * (CH * I_) + s * I_]);
    #pragma unroll
    for (int r = 0; r < 6; ++r) {
      const float4 v = q[r];
      xn[4*r] = v.x; xn[4*r+1] = v.y; xn[4*r+2] = v.z; xn[4*r+3] = v.w;
    }
  };

  f2 accig, accfo;
  auto XDOT = [&]() {
    f2 u0 = {0,0}, u1 = {0,0}, v0 = {0,0}, v1 = {0,0};
    #pragma unroll
    for (int k = 0; k < I_; k += 2) {
      u0 = pkfma(Wxig[k],     xn[k],     u0);
      u1 = pkfma(Wxig[k + 1], xn[k + 1], u1);
      v0 = pkfma(Wxfo[k],     xn[k],     v0);
      v1 = pkfma(Wxfo[k + 1], xn[k + 1], v1);
    }
    accig = big + (u0 + u1);
    accfo = bfo + (v0 + v1);
  };

  float hk[H_];
  #pragma unroll
  for (int k = 0; k < H_; ++k) hk[k] = 0.0f;
  float c = 0.0f, h = 0.0f;

  // --- prologue: stage chunk 0, prefetch chunk 1, acc for t=0 ---
  GLOAD(0);
  DSWRITE(0);
  GLOAD(1);
  READX(0, 0);
  XDOT();

  int t0 = 0;
  #pragma unroll 1
  for (int ci = 0;; ++ci, t0 += CH) {
    const int buf = ci & 1;
    const int rem = lenA - t0;
    const int sh = rem < CH ? rem : CH;

    #pragma unroll 1
    for (int s = 0; s < sh; ++s) {
      READX(buf, (s + 1 < CH) ? s + 1 : 0);       // x(t+1) (6 ds_read, hidden)
      // h-dot + gates: the critical chain (no cross-lane ops)
      f2 q0 = {0,0}, q1 = {0,0}, r0 = {0,0}, r1 = {0,0};
      #pragma unroll
      for (int k = 0; k < H_; k += 2) {
        q0 = pkfma(Whig[k],     hk[k],     q0);
        q1 = pkfma(Whig[k + 1], hk[k + 1], q1);
        r0 = pkfma(Whfo[k],     hk[k],     r0);
        r1 = pkfma(Whfo[k + 1], hk[k + 1], r1);
      }
      const f2 aig = accig + (q0 + q1);           // (i, g)
      const f2 afo = accfo + (r0 + r1);           // (f, o)
      const float si = sigm(aig.x);
      const float tg = tanh_fast(aig.y);
      const float sf = sigm(afo.x);
      const float so = sigm(afo.y);
      c = fmaf(sf, c, si * tg);
      h = so * tanh_fast(c);
      if (j < H_) { hst[hf][s][j] = h; hbuf[hf][j] = h; }
      // broadcast h for next step (same-wave DS pipe is in-order; latency
      // hidden under XDOT below)
      {
        const float4* hq = (const float4*)(&hbuf[hf][0]);
        #pragma unroll
        for (int r5 = 0; r5 < 5; ++r5) {
          const float4 hv = hq[r5];
          hk[4*r5] = hv.x; hk[4*r5+1] = hv.y; hk[4*r5+2] = hv.z; hk[4*r5+3] = hv.w;
        }
      }
      XDOT();                                     // acc for t+1 (off-chain)
    }

    // --- chunk flush: lane j handles (t0+j, b) for its half ---
    if (j < sh && (t0 + j) < len) {
      const float4* hq = (const float4*)(&hst[hf][j][0]);
      f2 pa = {0,0}, pb = {0,0};
      #pragma unroll
      for (int r5 = 0; r5 < 5; ++r5) {
        const float4 hv = hq[r5];
        pa = pkfma(wab[4*r5],     hv.x, pa);
        pb = pkfma(wab[4*r5 + 1], hv.y, pb);
        pa = pkfma(wab[4*r5 + 2], hv.z, pa);
        pb = pkfma(wab[4*r5 + 3], hv.w, pb);
      }
      const f2 pp = pa + pb;                      // (dot_a, dot_b)
      const size_t n = (size_t)(t0 + j) * B_ + b;
      out[n]       = __expf(pp.x + ba);
      out[TB_ + n] = softplus_fast(pp.y + bb);
    }

    if (t0 + sh >= lenA) break;

    // --- boundary: stage chunk ci+1, prefetch ci+2, cross-chunk acc ---
    DSWRITE(buf ^ 1);                 // p regs from GLOAD(ci+1), vmcnt ~free
    GLOAD(ci + 2);
    READX(buf ^ 1, 0);                // x(t0+CH)
    XDOT();
  }

  // --- tail: t >= len => constant outputs (per half, 32-lane stride) ---
  const float apad = __expf(ba);
  const float bpad = softplus_fast(bb);
  for (int t = len + j; t < T_; t += 32) {
    out[(size_t)t * B_ + b]       = apad;
    out[TB_ + (size_t)t * B_ + b] = bpad;
  }
}

extern "C" void kernel_launch(void* const* d_in, const int* in_sizes, int n_in,
                              void* d_out, int out_size, void* d_ws, size_t ws_size,
                              hipStream_t stream) {
  (void)in_sizes; (void)n_in; (void)out_size; (void)d_ws; (void)ws_size;
  lstm_fused<<<dim3(B_ / 2), dim3(64), 0, stream>>>(
      (const float*)d_in[0], (const int*)d_in[1],
      (const float*)d_in[2], (const float*)d_in[3],
      (const float*)d_in[4], (const float*)d_in[5],
      (const float*)d_in[6], (const float*)d_in[7],
      (const float*)d_in[8], (const float*)d_in[9],
      (float*)d_out);
}